// Round 5
// baseline (567.991 us; speedup 1.0000x reference)
//
#include <hip/hip_runtime.h>
#include <math.h>

#define N_  2
#define L_  512
#define CS  384
#define CZ  128
#define H_  12
#define D_  32
#define HD  384   // H_*D_

__device__ __forceinline__ float sigmoidf_(float x) { return 1.f / (1.f + __expf(-x)); }

// ---------------- K0: LayerNorm of s -> sn [N*L][CS] ----------------
__global__ __launch_bounds__(64) void k_ln_s(const float* __restrict__ s,
        const float* __restrict__ w, const float* __restrict__ b,
        float* __restrict__ sn) {
    int row = blockIdx.x;                 // 0..N*L-1
    const float* x = s + (size_t)row * CS;
    float* y = sn + (size_t)row * CS;
    int lane = threadIdx.x;
    float v[6];
    float sum = 0.f, sq = 0.f;
#pragma unroll
    for (int e = 0; e < 6; ++e) {
        v[e] = x[lane + e * 64];
        sum += v[e];
        sq  += v[e] * v[e];
    }
#pragma unroll
    for (int o = 1; o < 64; o <<= 1) {
        sum += __shfl_xor(sum, o);
        sq  += __shfl_xor(sq , o);
    }
    float m = sum * (1.f / CS);
    float var = sq * (1.f / CS) - m * m;
    float rstd = rsqrtf(var + 1e-5f);
#pragma unroll
    for (int e = 0; e < 6; ++e) {
        int c = lane + e * 64;
        y[c] = (v[e] - m) * rstd * w[c] + b[c];
    }
}

// ---------------- Kw: fold ln_z into wz ----------------
__global__ __launch_bounds__(128) void k_wz_prep(const float* __restrict__ lnzw,
        const float* __restrict__ lnzb, const float* __restrict__ wz,
        float* __restrict__ wzp, float* __restrict__ wzps, float* __restrict__ wzb) {
    __shared__ float sp[H_][CZ];
    __shared__ float sb[H_][CZ];
    int c = threadIdx.x; // 0..127
    float lw = lnzw[c], lb = lnzb[c];
    for (int h = 0; h < H_; ++h) {
        float w = wz[h * CZ + c];
        float p = lw * w;
        sp[h][c] = p;
        sb[h][c] = lb * w;
        wzp[h * CZ + c] = p;
    }
    __syncthreads();
    if (c < H_) {
        float s1 = 0.f, s2 = 0.f;
        for (int e = 0; e < CZ; ++e) { s1 += sp[c][e]; s2 += sb[c][e]; }
        wzps[c] = s1; wzb[c] = s2;
    }
}

// ---------------- K1: projections q,k,v,gpre = sn x {wq,wk,wv,wg} ----------------
__global__ __launch_bounds__(384) void k_proj(const float* __restrict__ sn,
        const float* __restrict__ wq, const float* __restrict__ wk,
        const float* __restrict__ wv, const float* __restrict__ wg,
        float* __restrict__ q, float* __restrict__ k, float* __restrict__ v,
        float* __restrict__ g) {
    __shared__ float s_lds[8][CS];
    int t = threadIdx.x;
    int row0 = blockIdx.x * 8;
    {
        const float4* src = (const float4*)(sn + (size_t)row0 * CS);
        float4* dst = (float4*)(&s_lds[0][0]);
        dst[t] = src[t];
        dst[t + 384] = src[t + 384];
    }
    __syncthreads();
    int mat = t / 96;
    int col = (t % 96) * 4;
    const float* W = (mat == 0) ? wq : (mat == 1) ? wk : (mat == 2) ? wv : wg;
    float acc[8][4];
#pragma unroll
    for (int r = 0; r < 8; ++r)
#pragma unroll
        for (int j = 0; j < 4; ++j) acc[r][j] = 0.f;
    for (int kk = 0; kk < CS; kk += 4) {
        float4 w0 = *(const float4*)(W + (size_t)(kk + 0) * HD + col);
        float4 w1 = *(const float4*)(W + (size_t)(kk + 1) * HD + col);
        float4 w2 = *(const float4*)(W + (size_t)(kk + 2) * HD + col);
        float4 w3 = *(const float4*)(W + (size_t)(kk + 3) * HD + col);
#pragma unroll
        for (int r = 0; r < 8; ++r) {
            float4 sv = *(const float4*)(&s_lds[r][kk]);
            acc[r][0] += sv.x * w0.x + sv.y * w1.x + sv.z * w2.x + sv.w * w3.x;
            acc[r][1] += sv.x * w0.y + sv.y * w1.y + sv.z * w2.y + sv.w * w3.y;
            acc[r][2] += sv.x * w0.z + sv.y * w1.z + sv.z * w2.z + sv.w * w3.z;
            acc[r][3] += sv.x * w0.w + sv.y * w1.w + sv.z * w2.w + sv.w * w3.w;
        }
    }
    float* out = (mat == 0) ? q : (mat == 1) ? k : (mat == 2) ? v : g;
    float scale = (mat == 0) ? 0.17677669529663687f : 1.f;  // 1/sqrt(32) on q
#pragma unroll
    for (int r = 0; r < 8; ++r) {
        float4 o;
        o.x = acc[r][0] * scale; o.y = acc[r][1] * scale;
        o.z = acc[r][2] * scale; o.w = acc[r][3] * scale;
        *(float4*)(out + (size_t)(row0 + r) * HD + col) = o;
    }
}

// ---------------- K2 v3: z -> pair bias, register-tiled 2 rows x 12 heads ----------------
// grid (4 jt, 512 i, 2 n), 256 threads. 128 z-rows staged, stride 130 floats
// (520B: quarter-wave b128 phases tile the 32 banks exactly 2x -> free regime).
__global__ __launch_bounds__(256) void k_bias(const float* __restrict__ z,
        const float* __restrict__ wzp, const float* __restrict__ wzps,
        const float* __restrict__ wzb, float* __restrict__ bias) {
    __shared__ float z_lds[128 * 130];
    __shared__ float w_lds[H_ * CZ];
    __shared__ float ws_lds[H_], wb_lds[H_];
    int t = threadIdx.x;
    int jt = blockIdx.x, i = blockIdx.y, n = blockIdx.z;
    int j0 = jt * 128;
    {   // stage folded weights (1536 floats = 384 float4) + per-head sums
        const float4* wsrc = (const float4*)wzp;
        float4* wdst = (float4*)w_lds;
        if (t < 128) {
            wdst[t] = wsrc[t];
            wdst[t + 128] = wsrc[t + 128];
            wdst[t + 256] = wsrc[t + 256];
        } else if (t < 128 + H_) {
            ws_lds[t - 128] = wzps[t - 128];
            wb_lds[t - 128] = wzb[t - 128];
        }
    }
    {   // stage 128 z rows = 4096 float4, padded stride 130 floats
        const float4* src = (const float4*)(z + ((size_t)(n * L_ + i) * L_ + j0) * CZ);
#pragma unroll
        for (int e = 0; e < 16; ++e) {
            int idx = t + e * 256;
            float4 vv = src[idx];
            *(float4*)(&z_lds[(idx >> 5) * 130 + (idx & 31) * 4]) = vv;
        }
    }
    __syncthreads();
    int l = t & 63, w = t >> 6;
    int jj = (l & 7) | ((l >> 5) << 3);   // 0..15
    int cs = (l >> 3) & 3;                // c-slice
    int r0 = w * 32 + jj * 2;             // block-local row (owns r0, r0+1)
    const float* zr0 = &z_lds[r0 * 130];
    const float* zr1 = zr0 + 130;
    float acc0[H_], acc1[H_];
#pragma unroll
    for (int h = 0; h < H_; ++h) { acc0[h] = 0.f; acc1[h] = 0.f; }
    float s10 = 0.f, s20 = 0.f, s11 = 0.f, s21 = 0.f;
#pragma unroll
    for (int k = 0; k < 8; ++k) {
        int col = cs * 4 + k * 16;        // interleaved c-slice
        float4 z0 = *(const float4*)(zr0 + col);
        float4 z1 = *(const float4*)(zr1 + col);
        s10 += z0.x + z0.y + z0.z + z0.w;
        s20 += z0.x * z0.x + z0.y * z0.y + z0.z * z0.z + z0.w * z0.w;
        s11 += z1.x + z1.y + z1.z + z1.w;
        s21 += z1.x * z1.x + z1.y * z1.y + z1.z * z1.z + z1.w * z1.w;
#pragma unroll
        for (int h = 0; h < H_; ++h) {
            float4 wv = *(const float4*)(&w_lds[h * CZ + col]);  // broadcast per 8-lane group
            acc0[h] += z0.x * wv.x + z0.y * wv.y + z0.z * wv.z + z0.w * wv.w;
            acc1[h] += z1.x * wv.x + z1.y * wv.y + z1.z * wv.z + z1.w * wv.w;
        }
    }
    // reduce partial sums across the 4 c-slices (lane bits 3,4)
#pragma unroll
    for (int h = 0; h < H_; ++h) {
        acc0[h] += __shfl_xor(acc0[h], 8);  acc0[h] += __shfl_xor(acc0[h], 16);
        acc1[h] += __shfl_xor(acc1[h], 8);  acc1[h] += __shfl_xor(acc1[h], 16);
    }
    s10 += __shfl_xor(s10, 8); s10 += __shfl_xor(s10, 16);
    s20 += __shfl_xor(s20, 8); s20 += __shfl_xor(s20, 16);
    s11 += __shfl_xor(s11, 8); s11 += __shfl_xor(s11, 16);
    s21 += __shfl_xor(s21, 8); s21 += __shfl_xor(s21, 16);
    float m0 = s10 * (1.f / CZ), m1 = s11 * (1.f / CZ);
    float rs0 = rsqrtf(s20 * (1.f / CZ) - m0 * m0 + 1e-5f);
    float rs1 = rsqrtf(s21 * (1.f / CZ) - m1 * m1 + 1e-5f);
    int jg = j0 + r0;
    // lane cs writes heads h with h&3==cs : 3 heads x 2 consecutive j's (float2, coalesced)
#pragma unroll
    for (int hh = 0; hh < 3; ++hh) {
        int h = hh * 4 + cs;
        float wsh = ws_lds[h], wbh = wb_lds[h];
        float2 bv;
        bv.x = rs0 * (acc0[h] - m0 * wsh) + wbh;
        bv.y = rs1 * (acc1[h] - m1 * wsh) + wbh;
        *(float2*)(&bias[(((size_t)n * H_ + h) * L_ + i) * L_ + jg]) = bv;
    }
}

// ---------------- K3 v2: attention, one wave per (i,h); p in registers ----------------
// block = 512 threads = 8 waves = 8 i-rows of one (n,h). grid (L/8, H, N).
__global__ __launch_bounds__(512) void k_attn(const float* __restrict__ q,
        const float* __restrict__ k, const float* __restrict__ v,
        const float* __restrict__ gpre, const float* __restrict__ bg,
        const float* __restrict__ bias, float* __restrict__ og) {
    __shared__ float t_lds[2][64][36];   // double-buffered 64-row x 32-float tile (+pad)
    int t = threadIdx.x;
    int lane = t & 63;
    int w = t >> 6;
    int it = blockIdx.x, h = blockIdx.y, n = blockIdx.z;
    int i = it * 8 + w;
    int srow = t >> 3, se = t & 7;       // staging: one float4 per thread

    const float* qrow = q + ((size_t)(n * L_) + i) * HD + h * D_;
    float4 qr[8];
#pragma unroll
    for (int d4 = 0; d4 < 8; ++d4) qr[d4] = *(const float4*)(qrow + d4 * 4);
    const float* brow = bias + (((size_t)n * H_ + h) * L_ + i) * L_;
    const float* kbase = k + (size_t)(n * L_) * HD + h * D_;
    const float* vbase = v + (size_t)(n * L_) * HD + h * D_;

    // ---- QK phase ----
    *(float4*)(&t_lds[0][srow][se * 4]) =
        *(const float4*)(kbase + (size_t)srow * HD + se * 4);
    __syncthreads();
    float p[8];
#pragma unroll
    for (int s = 0; s < 8; ++s) {
        float4 stg;
        if (s < 7)
            stg = *(const float4*)(kbase + (size_t)((s + 1) * 64 + srow) * HD + se * 4);
        float acc = brow[s * 64 + lane];
        const float* kr = &t_lds[s & 1][lane][0];
#pragma unroll
        for (int d4 = 0; d4 < 8; ++d4) {
            float4 kv = *(const float4*)(kr + d4 * 4);
            float4 qv = qr[d4];
            acc += qv.x * kv.x + qv.y * kv.y + qv.z * kv.z + qv.w * kv.w;
        }
        p[s] = acc;
        if (s < 7)
            *(float4*)(&t_lds[(s + 1) & 1][srow][se * 4]) = stg;
        __syncthreads();
    }
    // ---- softmax (fully in-wave) ----
    float mx = p[0];
#pragma unroll
    for (int s = 1; s < 8; ++s) mx = fmaxf(mx, p[s]);
#pragma unroll
    for (int o = 1; o < 64; o <<= 1) mx = fmaxf(mx, __shfl_xor(mx, o));
    float sum = 0.f;
#pragma unroll
    for (int s = 0; s < 8; ++s) { p[s] = __expf(p[s] - mx); sum += p[s]; }
#pragma unroll
    for (int o = 1; o < 64; o <<= 1) sum += __shfl_xor(sum, o);
    float rinv = 1.f / sum;

    // ---- PV phase ----
    float acc[32];
#pragma unroll
    for (int d = 0; d < 32; ++d) acc[d] = 0.f;
    *(float4*)(&t_lds[0][srow][se * 4]) =
        *(const float4*)(vbase + (size_t)srow * HD + se * 4);
    __syncthreads();
#pragma unroll
    for (int s = 0; s < 8; ++s) {
        float4 stg;
        if (s < 7)
            stg = *(const float4*)(vbase + (size_t)((s + 1) * 64 + srow) * HD + se * 4);
        float e = p[s];
        const float* vr = &t_lds[s & 1][lane][0];
#pragma unroll
        for (int d4 = 0; d4 < 8; ++d4) {
            float4 vv = *(const float4*)(vr + d4 * 4);
            acc[d4 * 4 + 0] += e * vv.x;
            acc[d4 * 4 + 1] += e * vv.y;
            acc[d4 * 4 + 2] += e * vv.z;
            acc[d4 * 4 + 3] += e * vv.w;
        }
        if (s < 7)
            *(float4*)(&t_lds[(s + 1) & 1][srow][se * 4]) = stg;
        __syncthreads();
    }
    // ---- butterfly-split reduce: 32 accs over 64 lanes -> lane holds d = lane&31 ----
    bool b0 = lane & 1, b1 = lane & 2, b2 = lane & 4, b3 = lane & 8, b4 = lane & 16;
    float r1[16];
#pragma unroll
    for (int m = 0; m < 16; ++m) {
        float give = b0 ? acc[2 * m] : acc[2 * m + 1];
        float got = __shfl_xor(give, 1);
        r1[m] = (b0 ? acc[2 * m + 1] : acc[2 * m]) + got;
    }
    float r2[8];
#pragma unroll
    for (int m = 0; m < 8; ++m) {
        float give = b1 ? r1[2 * m] : r1[2 * m + 1];
        float got = __shfl_xor(give, 2);
        r2[m] = (b1 ? r1[2 * m + 1] : r1[2 * m]) + got;
    }
    float r3[4];
#pragma unroll
    for (int m = 0; m < 4; ++m) {
        float give = b2 ? r2[2 * m] : r2[2 * m + 1];
        float got = __shfl_xor(give, 4);
        r3[m] = (b2 ? r2[2 * m + 1] : r2[2 * m]) + got;
    }
    float r4[2];
#pragma unroll
    for (int m = 0; m < 2; ++m) {
        float give = b3 ? r3[2 * m] : r3[2 * m + 1];
        float got = __shfl_xor(give, 8);
        r4[m] = (b3 ? r3[2 * m + 1] : r3[2 * m]) + got;
    }
    float give = b4 ? r4[0] : r4[1];
    float r5 = (b4 ? r4[1] : r4[0]) + __shfl_xor(give, 16);
    float oval = (r5 + __shfl_xor(r5, 32)) * rinv;

    if (lane < 32) {
        int d = lane;
        size_t gi = ((size_t)(n * L_) + i) * HD + h * D_ + d;
        float g = sigmoidf_(gpre[gi] + bg[h * D_ + d]);
        og[gi] = oval * g;
    }
}

// ---------------- K4: out = og x wo + bo ----------------
__global__ __launch_bounds__(384) void k_out(const float* __restrict__ og,
        const float* __restrict__ wo, const float* __restrict__ bo,
        float* __restrict__ out) {
    __shared__ float o_lds[8][HD];
    int t = threadIdx.x;
    int row0 = blockIdx.x * 8;
    {
        const float4* src = (const float4*)(og + (size_t)row0 * HD);
        float4* dst = (float4*)(&o_lds[0][0]);
        dst[t] = src[t];
        dst[t + 384] = src[t + 384];
    }
    __syncthreads();
    float acc[8];
#pragma unroll
    for (int r = 0; r < 8; ++r) acc[r] = 0.f;
    for (int kk = 0; kk < HD; kk += 4) {
        float w0 = wo[(size_t)(kk + 0) * CS + t];
        float w1 = wo[(size_t)(kk + 1) * CS + t];
        float w2 = wo[(size_t)(kk + 2) * CS + t];
        float w3 = wo[(size_t)(kk + 3) * CS + t];
#pragma unroll
        for (int r = 0; r < 8; ++r) {
            float4 ov = *(const float4*)(&o_lds[r][kk]);
            acc[r] += ov.x * w0 + ov.y * w1 + ov.z * w2 + ov.w * w3;
        }
    }
    float bv = bo[t];
#pragma unroll
    for (int r = 0; r < 8; ++r) out[(size_t)(row0 + r) * CS + t] = acc[r] + bv;
}

extern "C" void kernel_launch(void* const* d_in, const int* in_sizes, int n_in,
                              void* d_out, int out_size, void* d_ws, size_t ws_size,
                              hipStream_t stream) {
    const float* s    = (const float*)d_in[0];
    const float* z    = (const float*)d_in[1];
    const float* lnsw = (const float*)d_in[2];
    const float* lnsb = (const float*)d_in[3];
    const float* lnzw = (const float*)d_in[4];
    const float* lnzb = (const float*)d_in[5];
    const float* wz   = (const float*)d_in[6];
    const float* wq   = (const float*)d_in[7];
    const float* wk   = (const float*)d_in[8];
    const float* wv   = (const float*)d_in[9];
    const float* wg   = (const float*)d_in[10];
    const float* bg   = (const float*)d_in[11];
    const float* wo   = (const float*)d_in[12];
    const float* bo   = (const float*)d_in[13];
    float* out = (float*)d_out;

    float* ws = (float*)d_ws;
    const size_t NL = (size_t)N_ * L_;     // 1024
    float* sn   = ws;  ws += NL * CS;
    float* q    = ws;  ws += NL * HD;
    float* kk   = ws;  ws += NL * HD;
    float* vv   = ws;  ws += NL * HD;
    float* gpre = ws;  ws += NL * HD;
    float* og   = ws;  ws += NL * HD;
    float* wzp  = ws;  ws += H_ * CZ;
    float* wzps = ws;  ws += 16;
    float* wzb  = ws;  ws += 16;
    float* bias = ws;  // N_*H_*L_*L_ = 6291456 floats

    k_ln_s<<<dim3(NL), 64, 0, stream>>>(s, lnsw, lnsb, sn);
    k_wz_prep<<<dim3(1), 128, 0, stream>>>(lnzw, lnzb, wz, wzp, wzps, wzb);
    k_proj<<<dim3(128), 384, 0, stream>>>(sn, wq, wk, wv, wg, q, kk, vv, gpre);
    k_bias<<<dim3(4, 512, 2), 256, 0, stream>>>(z, wzp, wzps, wzb, bias);
    k_attn<<<dim3(64, 12, 2), 512, 0, stream>>>(q, kk, vv, gpre, bg, bias, og);
    k_out<<<dim3(128), 384, 0, stream>>>(og, wo, bo, out);
}